// Round 4
// baseline (17594.000 us; speedup 1.0000x reference)
//
#include <hip/hip_runtime.h>
#include <hip/hip_bf16.h>

#define NN 50000
#define TT 48
#define FIN 11
#define MB ((NN + 63) / 64)

typedef __bf16 bf16_t;
typedef __bf16 v8bf __attribute__((ext_vector_type(8)));
typedef float v4f __attribute__((ext_vector_type(4)));

__device__ __forceinline__ float sigm_(float x) {
  return 1.0f / (1.0f + __expf(-x));
}

#define MFMA16(A, B, C) C = __builtin_amdgcn_mfma_f32_16x16x32_bf16(A, B, C, 0, 0, 0)

// ---------------- weight packing: MFMA-fragment order, 1KB coalesced chunks ---
// PZ[w][kt][nf][zr][lane][8]   : z,r gates, K=288 (9 kts)  -> 147456 bf16
// PH[w][kt][nf][lane][8]       : h gate,    K=288          ->  73728 bf16
// PU[half][w][kt][nf8][lane][8]: u/sp z+h gates, K=256     -> 262144 bf16
// Byte-equivalent to reading W[c][k] with c=w*64+nf*16+(lane&15),
// k=kt*32+(lane>>4)*8+e  (the exact round-1 B-fragment access pattern).
__global__ void pack_w(const float* __restrict__ bbWx, const float* __restrict__ bbWh,
                       const float* __restrict__ uWx, const float* __restrict__ spWx,
                       bf16_t* __restrict__ PZ, bf16_t* __restrict__ PH,
                       bf16_t* __restrict__ PU) {
  int i0 = blockIdx.x * blockDim.x + threadIdx.x;
  int stride = gridDim.x * blockDim.x;
  for (int idx = i0; idx < 147456; idx += stride) {
    int ch = idx >> 9, r = idx & 511, lane = r >> 3, e = r & 7;
    int w = ch / 72, r72 = ch - w * 72, kt = r72 >> 3, r8 = r72 & 7, nf = r8 >> 1, zr = r8 & 1;
    int l15 = lane & 15, q = lane >> 4;
    int c = w * 64 + nf * 16 + l15;
    int k = kt * 32 + q * 8 + e;
    float v = 0.f;
    if (k < 256) v = bbWh[(zr * 256 + c) * 256 + k];
    else if (k < 256 + FIN) v = bbWx[(zr * 256 + c) * FIN + (k - 256)];
    PZ[idx] = (bf16_t)v;
  }
  for (int idx = i0; idx < 73728; idx += stride) {
    int ch = idx >> 9, r = idx & 511, lane = r >> 3, e = r & 7;
    int w = ch / 36, r36 = ch - w * 36, kt = r36 >> 2, nf = r36 & 3;
    int l15 = lane & 15, q = lane >> 4;
    int c = w * 64 + nf * 16 + l15;
    int k = kt * 32 + q * 8 + e;
    float v = 0.f;
    if (k < 256) v = bbWh[(512 + c) * 256 + k];
    else if (k < 256 + FIN) v = bbWx[(512 + c) * FIN + (k - 256)];
    PH[idx] = (bf16_t)v;
  }
  for (int idx = i0; idx < 262144; idx += stride) {
    int ch = idx >> 9, r = idx & 511, lane = r >> 3, e = r & 7;
    int half = ch >> 8, r256 = ch & 255, w = r256 >> 6, r64 = r256 & 63, kt = r64 >> 3, nf = r64 & 7;
    int l15 = lane & 15, q = lane >> 4;
    int j = w * 64 + (nf & 3) * 16 + l15;
    int gate = (nf >> 2) ? 2 : 0;
    int k = kt * 32 + q * 8 + e;
    const float* W = half ? spWx : uWx;
    PU[idx] = (bf16_t)W[(gate * 256 + j) * 256 + k];
  }
}

// ---------------- fused persistent sequence kernel ----------------
// One block = 64 rows for all 48 steps. H in LDS (XOR swizzle). Weights stream
// from L2 in fragment-packed 1KB coalesced chunks. z stays in registers.
// Heads: round-1-proven LDS hs tile (bf16, same swizzle) + per-thread dot.
__global__ __launch_bounds__(256, 2) void fused_seq(
    const float* __restrict__ X,
    const bf16_t* __restrict__ PZ, const bf16_t* __restrict__ PH,
    const bf16_t* __restrict__ PU,
    const float* __restrict__ bbx, const float* __restrict__ bbh,
    const float* __restrict__ ubx, const float* __restrict__ ubh,
    const float* __restrict__ spbx, const float* __restrict__ spbh,
    const float* __restrict__ Wu, const float* __restrict__ buv,
    const float* __restrict__ Ws, const float* __restrict__ bsv,
    const float* __restrict__ Wp, const float* __restrict__ bpv,
    float* __restrict__ out) {
  __shared__ __align__(16) bf16_t Hm[64 * 256];  // 32768 B, swizzled H tile
  __shared__ __align__(16) bf16_t Ha[64 * 32];   // 4096 B, aug cols (X|pad)
  __shared__ __align__(16) bf16_t Rm[64 * 256];  // 32768 B, rH tile / hs tile
  char* const Hmb = (char*)Hm;
  char* const Hab = (char*)Ha;
  char* const Rmb = (char*)Rm;

  const int tid = threadIdx.x;
  const int lane = tid & 63, l15 = tid & 15, quad = (tid & 63) >> 4, wave = tid >> 6;
  const int rowBase = blockIdx.x * 64;
  const int srow = tid >> 2, sj = tid & 3, sm = rowBase + srow;

  // ---- hoisted per-thread constants (t-invariant; values identical to
  //      round-1's in-loop global reads) ----
  float bz_[4], br_[4], bh_[4], ub0[4], ub1[4], sb0[4], sb1[4];
#pragma unroll
  for (int nf = 0; nf < 4; ++nf) {
    const int c = wave * 64 + nf * 16 + l15;
    bz_[nf] = bbx[c] + bbh[c];
    br_[nf] = bbx[256 + c] + bbh[256 + c];
    bh_[nf] = bbx[512 + c] + bbh[512 + c];
    ub0[nf] = ubx[c] + ubh[c];
    ub1[nf] = ubx[512 + c] + ubh[512 + c];
    sb0[nf] = spbx[c] + spbh[c];
    sb1[nf] = spbx[512 + c] + spbh[512 + c];
  }

  const bf16_t* const pz0 = PZ + wave * 36864 + lane * 8;
  const bf16_t* const ph0 = PH + wave * 18432 + lane * 8;
  const bf16_t* const pu0 = PU + wave * 32768 + lane * 8;
  const bf16_t* const pu1 = PU + (4 + wave) * 32768 + lane * 8;

  // ---- init: H = 0, aug = [X_0 | 0] ----
  {
    uint4 z4 = make_uint4(0u, 0u, 0u, 0u);
    for (int i = tid; i < 2048; i += 256) ((uint4*)Hmb)[i] = z4;
    ((uint4*)Hab)[tid] = z4;
  }
  __syncthreads();
  if (sm < NN) {
    bf16_t* xr = (bf16_t*)(Hab + (srow << 6));
    const float* xp = X + (long)sm * FIN;
    xr[sj] = (bf16_t)xp[sj];
    xr[sj + 4] = (bf16_t)xp[sj + 4];
    if (sj + 8 < FIN) xr[sj + 8] = (bf16_t)xp[sj + 8];
  }
  __syncthreads();

#pragma unroll 1
  for (int t = 0; t < TT; ++t) {
    // ============ phase 1: z,r gemms (K=288, 9 kts) ============
    v4f az[4][4] = {}, ar[4][4] = {};
#pragma unroll
    for (int kt = 0; kt < 9; ++kt) {
      v8bf a[4];
#pragma unroll
      for (int mf = 0; mf < 4; ++mf) {
        if (kt < 8)
          a[mf] = *(const v8bf*)(Hmb + ((mf * 16 + l15) << 9) +
                                 ((kt * 64 + quad * 16) ^ ((l15 & 7) << 4)));
        else
          a[mf] = *(const v8bf*)(Hab + ((mf * 16 + l15) << 6) + quad * 16);
      }
      const bf16_t* p = pz0 + kt * 4096;
      v8bf bz[4], br[4];
#pragma unroll
      for (int nf = 0; nf < 4; ++nf) {
        bz[nf] = *(const v8bf*)(p + nf * 1024);
        br[nf] = *(const v8bf*)(p + nf * 1024 + 512);
      }
#pragma unroll
      for (int mf = 0; mf < 4; ++mf)
#pragma unroll
        for (int nf = 0; nf < 4; ++nf) {
          MFMA16(a[mf], bz[nf], az[mf][nf]);
          MFMA16(a[mf], br[nf], ar[mf][nf]);
        }
    }
    // epi1: z -> regs; rH -> Rm (all 64 rows)
    v4f zreg[4][4];
#pragma unroll
    for (int nf = 0; nf < 4; ++nf) {
      const int c = wave * 64 + nf * 16 + l15;
#pragma unroll
      for (int mf = 0; mf < 4; ++mf)
#pragma unroll
        for (int rg = 0; rg < 4; ++rg) {
          const int m = mf * 16 + quad * 4 + rg;
          zreg[mf][nf][rg] = sigm_(az[mf][nf][rg] + bz_[nf]);
          const int off = (m << 9) + ((c * 2) ^ ((m & 7) << 4));
          const float hp = (float)*(const bf16_t*)(Hmb + off);
          *(bf16_t*)(Rmb + off) = (bf16_t)(sigm_(ar[mf][nf][rg] + br_[nf]) * hp);
        }
    }
    __syncthreads();  // BAR1

    // prefetch X_{t+1} into registers (hides under phase-2 gemm)
    float xv0 = 0.f, xv1 = 0.f, xv2 = 0.f;
    if (t + 1 < TT && sm < NN) {
      const float* xp = X + ((long)(t + 1) * NN + sm) * FIN;
      xv0 = xp[sj];
      xv1 = xp[sj + 4];
      if (sj + 8 < FIN) xv2 = xp[sj + 8];
    }

    // ============ phase 2: h_tilde gemm (K=288) + blend ============
    v4f ah[4][4] = {};
#pragma unroll
    for (int kt = 0; kt < 9; ++kt) {
      v8bf a[4];
#pragma unroll
      for (int mf = 0; mf < 4; ++mf) {
        if (kt < 8)
          a[mf] = *(const v8bf*)(Rmb + ((mf * 16 + l15) << 9) +
                                 ((kt * 64 + quad * 16) ^ ((l15 & 7) << 4)));
        else
          a[mf] = *(const v8bf*)(Hab + ((mf * 16 + l15) << 6) + quad * 16);
      }
      const bf16_t* p = ph0 + kt * 2048;
      v8bf bh[4];
#pragma unroll
      for (int nf = 0; nf < 4; ++nf) bh[nf] = *(const v8bf*)(p + nf * 512);
#pragma unroll
      for (int mf = 0; mf < 4; ++mf)
#pragma unroll
        for (int nf = 0; nf < 4; ++nf) MFMA16(a[mf], bh[nf], ah[mf][nf]);
    }
    // epi2: Hm = z*Hm + (1-z)*tanh(ah+b)
#pragma unroll
    for (int nf = 0; nf < 4; ++nf) {
      const int c = wave * 64 + nf * 16 + l15;
#pragma unroll
      for (int mf = 0; mf < 4; ++mf)
#pragma unroll
        for (int rg = 0; rg < 4; ++rg) {
          const int m = mf * 16 + quad * 4 + rg;
          const int off = (m << 9) + ((c * 2) ^ ((m & 7) << 4));
          const float htl = tanhf(ah[mf][nf][rg] + bh_[nf]);
          const float z = zreg[mf][nf][rg];
          const float hp = (float)*(const bf16_t*)(Hmb + off);
          *(bf16_t*)(Hmb + off) = (bf16_t)(z * hp + (1.f - z) * htl);
        }
    }
    __syncthreads();  // BAR2

    // stage X_{t+1} into Ha (readers are next-t phases, behind later barriers)
    {
      bf16_t* xr = (bf16_t*)(Hab + (srow << 6));
      xr[sj] = (bf16_t)xv0;
      xr[sj + 4] = (bf16_t)xv1;
      if (sj + 8 < FIN) xr[sj + 8] = (bf16_t)xv2;
    }

    // ============ phase 3: gru_u / gru_sp (H=None) + heads ============
#pragma unroll
    for (int half = 0; half < 2; ++half) {
      const bf16_t* puh = half ? pu1 : pu0;
      v4f au[4][8] = {};
#pragma unroll
      for (int kt = 0; kt < 8; ++kt) {
        v8bf a[4];
#pragma unroll
        for (int mf = 0; mf < 4; ++mf)
          a[mf] = *(const v8bf*)(Hmb + ((mf * 16 + l15) << 9) +
                                 ((kt * 64 + quad * 16) ^ ((l15 & 7) << 4)));
        const bf16_t* p = puh + kt * 4096;
        v8bf bu[8];
#pragma unroll
        for (int nf = 0; nf < 8; ++nf) bu[nf] = *(const v8bf*)(p + nf * 512);
#pragma unroll
        for (int mf = 0; mf < 4; ++mf)
#pragma unroll
          for (int nf = 0; nf < 8; ++nf) MFMA16(a[mf], bu[nf], au[mf][nf]);
      }
      // epi: hs = (1-z)*h~ -> Rm (bf16, same swizzle as everywhere)
#pragma unroll
      for (int nf = 0; nf < 4; ++nf) {
        const float b0 = half ? sb0[nf] : ub0[nf];
        const float b1 = half ? sb1[nf] : ub1[nf];
        const int j = wave * 64 + nf * 16 + l15;
#pragma unroll
        for (int mf = 0; mf < 4; ++mf)
#pragma unroll
          for (int rg = 0; rg < 4; ++rg) {
            const int r = mf * 16 + quad * 4 + rg;
            const float zz = sigm_(au[mf][nf][rg] + b0);
            const float ht = tanhf(au[mf][nf + 4][rg] + b1);
            *(bf16_t*)(Rmb + (r << 9) + ((j * 2) ^ ((r & 7) << 4))) =
                (bf16_t)((1.f - zz) * ht);
          }
      }
      __syncthreads();  // hs tile ready
      if (half == 0) {
        if (tid < 192) {
          const int r = tid / 3, k = tid - r * 3, m = rowBase + r;
          if (m < NN) {
            float s = 0.f;
            for (int j = 0; j < 256; j += 8) {
              v8bf hv = *(const v8bf*)(Rmb + (r << 9) + ((j * 2) ^ ((r & 7) << 4)));
              const float* w = Wu + k * 256 + j;
#pragma unroll
              for (int jj = 0; jj < 8; ++jj) s += (float)hv[jj] * w[jj];
            }
            out[(long)t * (NN * 3) + (long)m * 3 + k] = s + buv[k];
          }
        }
      } else {
        if (tid < 128) {
          const int r = tid >> 1, which = tid & 1, m = rowBase + r;
          if (m < NN) {
            const float* W = which ? Wp : Ws;
            float s = 0.f;
            for (int j = 0; j < 256; j += 8) {
              v8bf hv = *(const v8bf*)(Rmb + (r << 9) + ((j * 2) ^ ((r & 7) << 4)));
#pragma unroll
              for (int jj = 0; jj < 8; ++jj) s += (float)hv[jj] * W[j + jj];
            }
            s += which ? bpv[0] : bsv[0];
            out[(long)TT * NN * 3 + (long)which * TT * NN + (long)t * NN + m] = s;
          }
        }
      }
      __syncthreads();  // head reads done before Rm is overwritten
    }
  }
}

extern "C" void kernel_launch(void* const* d_in, const int* in_sizes, int n_in,
                              void* d_out, int out_size, void* d_ws, size_t ws_size,
                              hipStream_t stream) {
  const float* X    = (const float*)d_in[0];
  // d_in[1] edge_index: unused (ChebConv K=1 ignores edges)
  const float* bbWx = (const float*)d_in[2];
  const float* bbbx = (const float*)d_in[3];
  const float* bbWh = (const float*)d_in[4];
  const float* bbbh = (const float*)d_in[5];
  const float* uWx  = (const float*)d_in[6];
  const float* ubx  = (const float*)d_in[7];
  const float* ubh  = (const float*)d_in[9];   // u_Wh (d_in[8]) dead: H=None
  const float* spWx = (const float*)d_in[10];
  const float* spbx = (const float*)d_in[11];
  const float* spbh = (const float*)d_in[13];  // sp_Wh (d_in[12]) dead
  const float* Wu   = (const float*)d_in[14];
  const float* buv  = (const float*)d_in[15];
  const float* Ws   = (const float*)d_in[16];
  const float* bsv  = (const float*)d_in[17];
  const float* Wp   = (const float*)d_in[18];
  const float* bpv  = (const float*)d_in[19];
  float* out = (float*)d_out;

  char* ws = (char*)d_ws;
  bf16_t* PZ = (bf16_t*)(ws);                  // 147456*2 = 294912
  bf16_t* PH = (bf16_t*)(ws + 294912);         //  73728*2 = 147456
  bf16_t* PU = (bf16_t*)(ws + 442368);         // 262144*2 = 524288
  if (ws_size < (size_t)966656) return;

  pack_w<<<dim3(192), dim3(256), 0, stream>>>(bbWx, bbWh, uWx, spWx, PZ, PH, PU);
  fused_seq<<<dim3(MB), dim3(256), 0, stream>>>(X, PZ, PH, PU, bbbx, bbbh,
                                                ubx, ubh, spbx, spbh,
                                                Wu, buv, Ws, bsv, Wp, bpv, out);
}

// Round 5
// 15287.456 us; speedup vs baseline: 1.1509x; 1.1509x over previous
//
#include <hip/hip_runtime.h>
#include <hip/hip_bf16.h>

#define NN 50000
#define TT 48
#define FIN 11
#define MB ((NN + 63) / 64)

typedef __bf16 bf16_t;
typedef __bf16 v8bf __attribute__((ext_vector_type(8)));
typedef __bf16 v2bf __attribute__((ext_vector_type(2)));
typedef float v4f __attribute__((ext_vector_type(4)));

__device__ __forceinline__ float sigm_(float x) {
  return 1.0f / (1.0f + __expf(-x));
}

#define MFMA16(A, B, C) C = __builtin_amdgcn_mfma_f32_16x16x32_bf16(A, B, C, 0, 0, 0)

// ---------------- weight packing: MFMA-fragment order, 1KB coalesced chunks ---
// PZ[w][kt][nf][zr][lane][8]   : z,r gates, K=288 (9 kts)  -> 147456 bf16
// PH[w][kt][nf][lane][8]       : h gate,    K=288          ->  73728 bf16
// PU[half][w][kt][nf8][lane][8]: u/sp z+h gates, K=256     -> 262144 bf16
// Byte-equivalent to reading W[c][k] with c=w*64+nf*16+(lane&15),
// k=kt*32+(lane>>4)*8+e  (the round-1 B-fragment access pattern).
__global__ void pack_w(const float* __restrict__ bbWx, const float* __restrict__ bbWh,
                       const float* __restrict__ uWx, const float* __restrict__ spWx,
                       bf16_t* __restrict__ PZ, bf16_t* __restrict__ PH,
                       bf16_t* __restrict__ PU) {
  int i0 = blockIdx.x * blockDim.x + threadIdx.x;
  int stride = gridDim.x * blockDim.x;
  for (int idx = i0; idx < 147456; idx += stride) {
    int ch = idx >> 9, r = idx & 511, lane = r >> 3, e = r & 7;
    int w = ch / 72, r72 = ch - w * 72, kt = r72 >> 3, r8 = r72 & 7, nf = r8 >> 1, zr = r8 & 1;
    int l15 = lane & 15, q = lane >> 4;
    int c = w * 64 + nf * 16 + l15;
    int k = kt * 32 + q * 8 + e;
    float v = 0.f;
    if (k < 256) v = bbWh[(zr * 256 + c) * 256 + k];
    else if (k < 256 + FIN) v = bbWx[(zr * 256 + c) * FIN + (k - 256)];
    PZ[idx] = (bf16_t)v;
  }
  for (int idx = i0; idx < 73728; idx += stride) {
    int ch = idx >> 9, r = idx & 511, lane = r >> 3, e = r & 7;
    int w = ch / 36, r36 = ch - w * 36, kt = r36 >> 2, nf = r36 & 3;
    int l15 = lane & 15, q = lane >> 4;
    int c = w * 64 + nf * 16 + l15;
    int k = kt * 32 + q * 8 + e;
    float v = 0.f;
    if (k < 256) v = bbWh[(512 + c) * 256 + k];
    else if (k < 256 + FIN) v = bbWx[(512 + c) * FIN + (k - 256)];
    PH[idx] = (bf16_t)v;
  }
  for (int idx = i0; idx < 262144; idx += stride) {
    int ch = idx >> 9, r = idx & 511, lane = r >> 3, e = r & 7;
    int half = ch >> 8, r256 = ch & 255, w = r256 >> 6, r64 = r256 & 63, kt = r64 >> 3, nf = r64 & 7;
    int l15 = lane & 15, q = lane >> 4;
    int j = w * 64 + (nf & 3) * 16 + l15;
    int gate = (nf >> 2) ? 2 : 0;
    int k = kt * 32 + q * 8 + e;
    const float* W = half ? spWx : uWx;
    PU[idx] = (bf16_t)W[(gate * 256 + j) * 256 + k];
  }
}

// ---------------- fused persistent sequence kernel ----------------
// One block = 64 rows for all 48 steps. H in LDS (XOR swizzle). Weights stream
// from L2 in fragment-packed 1KB coalesced chunks. Every GEMM is SINGLE-
// accumulator (two sequential passes where round 4 ran two at once): peak
// AGPR 64 + VGPR ~110 < 256/wave unified budget at 2 blocks/CU -> no spills.
__global__ __launch_bounds__(256, 2) void fused_seq(
    const float* __restrict__ X,
    const bf16_t* __restrict__ PZ, const bf16_t* __restrict__ PH,
    const bf16_t* __restrict__ PU,
    const float* __restrict__ bbx, const float* __restrict__ bbh,
    const float* __restrict__ ubx, const float* __restrict__ ubh,
    const float* __restrict__ spbx, const float* __restrict__ spbh,
    const float* __restrict__ Wu, const float* __restrict__ buv,
    const float* __restrict__ Ws, const float* __restrict__ bsv,
    const float* __restrict__ Wp, const float* __restrict__ bpv,
    float* __restrict__ out) {
  __shared__ __align__(16) bf16_t Hm[64 * 256];  // 32768 B, swizzled H tile
  __shared__ __align__(16) bf16_t Ha[64 * 32];   // 4096 B, aug cols (X|pad)
  __shared__ __align__(16) bf16_t Rm[64 * 256];  // 32768 B, rH / zz / hs tile
  char* const Hmb = (char*)Hm;
  char* const Hab = (char*)Ha;
  char* const Rmb = (char*)Rm;

  const int tid = threadIdx.x;
  const int lane = tid & 63, l15 = tid & 15, quad = (tid & 63) >> 4, wave = tid >> 6;
  const int rowBase = blockIdx.x * 64;
  const int srow = tid >> 2, sj = tid & 3, sm = rowBase + srow;

  const bf16_t* const pz0 = PZ + wave * 36864 + lane * 8;
  const bf16_t* const ph0 = PH + wave * 18432 + lane * 8;
  const bf16_t* const pu0 = PU + wave * 32768 + lane * 8;
  const bf16_t* const pu1 = PU + (4 + wave) * 32768 + lane * 8;

  // ---- init: H = 0, aug = [X_0 | 0] ----
  {
    uint4 z4 = make_uint4(0u, 0u, 0u, 0u);
    for (int i = tid; i < 2048; i += 256) ((uint4*)Hmb)[i] = z4;
    ((uint4*)Hab)[tid] = z4;
  }
  __syncthreads();
  if (sm < NN) {
    bf16_t* xr = (bf16_t*)(Hab + (srow << 6));
    const float* xp = X + (long)sm * FIN;
    xr[sj] = (bf16_t)xp[sj];
    xr[sj + 4] = (bf16_t)xp[sj + 4];
    if (sj + 8 < FIN) xr[sj + 8] = (bf16_t)xp[sj + 8];
  }
  __syncthreads();

#pragma unroll 1
  for (int t = 0; t < TT; ++t) {
    v2bf zpk[4][4][2];  // z gate, bf16-packed (32 VGPRs), lives through phase 2

    // ============ phase 1a: z-gemm (K=288, single accumulator) ============
    {
      v4f az[4][4] = {};
#pragma unroll
      for (int kt = 0; kt < 9; ++kt) {
        v8bf a[4];
#pragma unroll
        for (int mf = 0; mf < 4; ++mf) {
          if (kt < 8)
            a[mf] = *(const v8bf*)(Hmb + ((mf * 16 + l15) << 9) +
                                   ((kt * 64 + quad * 16) ^ ((l15 & 7) << 4)));
          else
            a[mf] = *(const v8bf*)(Hab + ((mf * 16 + l15) << 6) + quad * 16);
        }
        const bf16_t* p = pz0 + kt * 4096;
        v8bf bz[4];
#pragma unroll
        for (int nf = 0; nf < 4; ++nf) bz[nf] = *(const v8bf*)(p + nf * 1024);
#pragma unroll
        for (int mf = 0; mf < 4; ++mf)
#pragma unroll
          for (int nf = 0; nf < 4; ++nf) MFMA16(a[mf], bz[nf], az[mf][nf]);
      }
#pragma unroll
      for (int nf = 0; nf < 4; ++nf) {
        const int c = wave * 64 + nf * 16 + l15;
        const float bz_ = bbx[c] + bbh[c];
#pragma unroll
        for (int mf = 0; mf < 4; ++mf)
#pragma unroll
          for (int rg = 0; rg < 4; ++rg)
            zpk[mf][nf][rg >> 1][rg & 1] = (bf16_t)sigm_(az[mf][nf][rg] + bz_);
      }
    }

    // ============ phase 1b: r-gemm (single accumulator) ============
    {
      v4f ar[4][4] = {};
#pragma unroll
      for (int kt = 0; kt < 9; ++kt) {
        v8bf a[4];
#pragma unroll
        for (int mf = 0; mf < 4; ++mf) {
          if (kt < 8)
            a[mf] = *(const v8bf*)(Hmb + ((mf * 16 + l15) << 9) +
                                   ((kt * 64 + quad * 16) ^ ((l15 & 7) << 4)));
          else
            a[mf] = *(const v8bf*)(Hab + ((mf * 16 + l15) << 6) + quad * 16);
        }
        const bf16_t* p = pz0 + kt * 4096 + 512;
        v8bf br[4];
#pragma unroll
        for (int nf = 0; nf < 4; ++nf) br[nf] = *(const v8bf*)(p + nf * 1024);
#pragma unroll
        for (int mf = 0; mf < 4; ++mf)
#pragma unroll
          for (int nf = 0; nf < 4; ++nf) MFMA16(a[mf], br[nf], ar[mf][nf]);
      }
      // epi: rH -> Rm
#pragma unroll
      for (int nf = 0; nf < 4; ++nf) {
        const int c = wave * 64 + nf * 16 + l15;
        const float br_ = bbx[256 + c] + bbh[256 + c];
#pragma unroll
        for (int mf = 0; mf < 4; ++mf)
#pragma unroll
          for (int rg = 0; rg < 4; ++rg) {
            const int m = mf * 16 + quad * 4 + rg;
            const int off = (m << 9) + ((c * 2) ^ ((m & 7) << 4));
            const float hp = (float)*(const bf16_t*)(Hmb + off);
            *(bf16_t*)(Rmb + off) = (bf16_t)(sigm_(ar[mf][nf][rg] + br_) * hp);
          }
      }
    }
    __syncthreads();  // BAR1

    // prefetch X_{t+1} into registers (hides under phase-2 gemm)
    float xv0 = 0.f, xv1 = 0.f, xv2 = 0.f;
    if (t + 1 < TT && sm < NN) {
      const float* xp = X + ((long)(t + 1) * NN + sm) * FIN;
      xv0 = xp[sj];
      xv1 = xp[sj + 4];
      if (sj + 8 < FIN) xv2 = xp[sj + 8];
    }

    // ============ phase 2: h_tilde gemm (K=288) + blend ============
    {
      v4f ah[4][4] = {};
#pragma unroll
      for (int kt = 0; kt < 9; ++kt) {
        v8bf a[4];
#pragma unroll
        for (int mf = 0; mf < 4; ++mf) {
          if (kt < 8)
            a[mf] = *(const v8bf*)(Rmb + ((mf * 16 + l15) << 9) +
                                   ((kt * 64 + quad * 16) ^ ((l15 & 7) << 4)));
          else
            a[mf] = *(const v8bf*)(Hab + ((mf * 16 + l15) << 6) + quad * 16);
        }
        const bf16_t* p = ph0 + kt * 2048;
        v8bf bh[4];
#pragma unroll
        for (int nf = 0; nf < 4; ++nf) bh[nf] = *(const v8bf*)(p + nf * 512);
#pragma unroll
        for (int mf = 0; mf < 4; ++mf)
#pragma unroll
          for (int nf = 0; nf < 4; ++nf) MFMA16(a[mf], bh[nf], ah[mf][nf]);
      }
      // epi2: Hm = z*Hm + (1-z)*tanh(ah+b)
#pragma unroll
      for (int nf = 0; nf < 4; ++nf) {
        const int c = wave * 64 + nf * 16 + l15;
        const float bh_ = bbx[512 + c] + bbh[512 + c];
#pragma unroll
        for (int mf = 0; mf < 4; ++mf)
#pragma unroll
          for (int rg = 0; rg < 4; ++rg) {
            const int m = mf * 16 + quad * 4 + rg;
            const int off = (m << 9) + ((c * 2) ^ ((m & 7) << 4));
            const float htl = tanhf(ah[mf][nf][rg] + bh_);
            const float z = (float)zpk[mf][nf][rg >> 1][rg & 1];
            const float hp = (float)*(const bf16_t*)(Hmb + off);
            *(bf16_t*)(Hmb + off) = (bf16_t)(z * hp + (1.f - z) * htl);
          }
      }
    }
    __syncthreads();  // BAR2

    // stage X_{t+1} into Ha (readers: next-t phases, behind later barriers)
    {
      bf16_t* xr = (bf16_t*)(Hab + (srow << 6));
      xr[sj] = (bf16_t)xv0;
      xr[sj + 4] = (bf16_t)xv1;
      if (sj + 8 < FIN) xr[sj + 8] = (bf16_t)xv2;
    }

    // ============ phase 3: gru_u / gru_sp (H=None) + heads ============
#pragma unroll 1
    for (int half = 0; half < 2; ++half) {
      const bf16_t* puh = half ? pu1 : pu0;
      const float* gbx = half ? spbx : ubx;
      const float* gbh = half ? spbh : ubh;
      // ---- z-gate pass: zz -> Rm (own cells) ----
      {
        v4f au[4][4] = {};
#pragma unroll
        for (int kt = 0; kt < 8; ++kt) {
          v8bf a[4];
#pragma unroll
          for (int mf = 0; mf < 4; ++mf)
            a[mf] = *(const v8bf*)(Hmb + ((mf * 16 + l15) << 9) +
                                   ((kt * 64 + quad * 16) ^ ((l15 & 7) << 4)));
          const bf16_t* p = puh + kt * 4096;
          v8bf bu[4];
#pragma unroll
          for (int nf = 0; nf < 4; ++nf) bu[nf] = *(const v8bf*)(p + nf * 512);
#pragma unroll
          for (int mf = 0; mf < 4; ++mf)
#pragma unroll
            for (int nf = 0; nf < 4; ++nf) MFMA16(a[mf], bu[nf], au[mf][nf]);
        }
#pragma unroll
        for (int nf = 0; nf < 4; ++nf) {
          const int j = wave * 64 + nf * 16 + l15;
          const float b0 = gbx[j] + gbh[j];
#pragma unroll
          for (int mf = 0; mf < 4; ++mf)
#pragma unroll
            for (int rg = 0; rg < 4; ++rg) {
              const int r = mf * 16 + quad * 4 + rg;
              *(bf16_t*)(Rmb + (r << 9) + ((j * 2) ^ ((r & 7) << 4))) =
                  (bf16_t)sigm_(au[mf][nf][rg] + b0);
            }
        }
      }
      // ---- h-gate pass: hs = (1-zz)*tanh -> Rm (same own cells) ----
      {
        v4f au[4][4] = {};
#pragma unroll
        for (int kt = 0; kt < 8; ++kt) {
          v8bf a[4];
#pragma unroll
          for (int mf = 0; mf < 4; ++mf)
            a[mf] = *(const v8bf*)(Hmb + ((mf * 16 + l15) << 9) +
                                   ((kt * 64 + quad * 16) ^ ((l15 & 7) << 4)));
          const bf16_t* p = puh + kt * 4096 + 2048;
          v8bf bu[4];
#pragma unroll
          for (int nf = 0; nf < 4; ++nf) bu[nf] = *(const v8bf*)(p + nf * 512);
#pragma unroll
          for (int mf = 0; mf < 4; ++mf)
#pragma unroll
            for (int nf = 0; nf < 4; ++nf) MFMA16(a[mf], bu[nf], au[mf][nf]);
        }
#pragma unroll
        for (int nf = 0; nf < 4; ++nf) {
          const int j = wave * 64 + nf * 16 + l15;
          const float b1 = gbx[512 + j] + gbh[512 + j];
#pragma unroll
          for (int mf = 0; mf < 4; ++mf)
#pragma unroll
            for (int rg = 0; rg < 4; ++rg) {
              const int r = mf * 16 + quad * 4 + rg;
              bf16_t* cell = (bf16_t*)(Rmb + (r << 9) + ((j * 2) ^ ((r & 7) << 4)));
              const float zz = (float)*cell;  // own cell, written by this thread
              const float ht = tanhf(au[mf][nf][rg] + b1);
              *cell = (bf16_t)((1.f - zz) * ht);
            }
        }
      }
      __syncthreads();  // hs tile ready
      if (half == 0) {
        if (tid < 192) {
          const int r = tid / 3, k = tid - r * 3, m = rowBase + r;
          if (m < NN) {
            float s = 0.f;
            for (int j = 0; j < 256; j += 8) {
              v8bf hv = *(const v8bf*)(Rmb + (r << 9) + ((j * 2) ^ ((r & 7) << 4)));
              const float* w = Wu + k * 256 + j;
#pragma unroll
              for (int jj = 0; jj < 8; ++jj) s += (float)hv[jj] * w[jj];
            }
            out[(long)t * (NN * 3) + (long)m * 3 + k] = s + buv[k];
          }
        }
      } else {
        if (tid < 128) {
          const int r = tid >> 1, which = tid & 1, m = rowBase + r;
          if (m < NN) {
            const float* W = which ? Wp : Ws;
            float s = 0.f;
            for (int j = 0; j < 256; j += 8) {
              v8bf hv = *(const v8bf*)(Rmb + (r << 9) + ((j * 2) ^ ((r & 7) << 4)));
#pragma unroll
              for (int jj = 0; jj < 8; ++jj) s += (float)hv[jj] * W[j + jj];
            }
            s += which ? bpv[0] : bsv[0];
            out[(long)TT * NN * 3 + (long)which * TT * NN + (long)t * NN + m] = s;
          }
        }
      }
      __syncthreads();  // head reads done before Rm is overwritten
    }
  }
}

extern "C" void kernel_launch(void* const* d_in, const int* in_sizes, int n_in,
                              void* d_out, int out_size, void* d_ws, size_t ws_size,
                              hipStream_t stream) {
  const float* X    = (const float*)d_in[0];
  // d_in[1] edge_index: unused (ChebConv K=1 ignores edges)
  const float* bbWx = (const float*)d_in[2];
  const float* bbbx = (const float*)d_in[3];
  const float* bbWh = (const float*)d_in[4];
  const float* bbbh = (const float*)d_in[5];
  const float* uWx  = (const float*)d_in[6];
  const float* ubx  = (const float*)d_in[7];
  const float* ubh  = (const float*)d_in[9];   // u_Wh (d_in[8]) dead: H=None
  const float* spWx = (const float*)d_in[10];
  const float* spbx = (const float*)d_in[11];
  const float* spbh = (const float*)d_in[13];  // sp_Wh (d_in[12]) dead
  const float* Wu   = (const float*)d_in[14];
  const float* buv  = (const float*)d_in[15];
  const float* Ws   = (const float*)d_in[16];
  const float* bsv  = (const float*)d_in[17];
  const float* Wp   = (const float*)d_in[18];
  const float* bpv  = (const float*)d_in[19];
  float* out = (float*)d_out;

  char* ws = (char*)d_ws;
  bf16_t* PZ = (bf16_t*)(ws);                  // 147456*2 = 294912
  bf16_t* PH = (bf16_t*)(ws + 294912);         //  73728*2 = 147456
  bf16_t* PU = (bf16_t*)(ws + 442368);         // 262144*2 = 524288
  if (ws_size < (size_t)966656) return;

  pack_w<<<dim3(192), dim3(256), 0, stream>>>(bbWx, bbWh, uWx, spWx, PZ, PH, PU);
  fused_seq<<<dim3(MB), dim3(256), 0, stream>>>(X, PZ, PH, PU, bbbx, bbbh,
                                                ubx, ubh, spbx, spbh,
                                                Wu, buv, Ws, bsv, Wp, bpv, out);
}

// Round 7
// 10701.247 us; speedup vs baseline: 1.6441x; 1.4286x over previous
//
#include <hip/hip_runtime.h>
#include <hip/hip_bf16.h>

#define NN 50000
#define TT 48
#define FIN 11
#define MB ((NN + 63) / 64)

typedef __bf16 bf16_t;
typedef __bf16 v8bf __attribute__((ext_vector_type(8)));
typedef __bf16 v2bf __attribute__((ext_vector_type(2)));
typedef float v4f __attribute__((ext_vector_type(4)));

__device__ __forceinline__ float sigm_(float x) {
  return __builtin_amdgcn_rcpf(1.0f + __expf(-x));
}
__device__ __forceinline__ float tanh_(float x) {
  return 1.0f - 2.0f * __builtin_amdgcn_rcpf(1.0f + __expf(2.0f * x));
}

#define MFMA16(A, B, C) C = __builtin_amdgcn_mfma_f32_16x16x32_bf16(A, B, C, 0, 0, 0)

// ---------------- weight packing: 8-wave MFMA-fragment order -----------------
// Each wave owns a 32-col strip (nf=0,1). 1KB contiguous chunk per fragment.
// PZ[w8][kt9][nf2][zr2][lane64][8]   -> 147456 bf16
// PH[w8][kt9][nf2][lane64][8]        ->  73728 bf16
// PU[half2][w8][kt8][g2][nf2][ln][8] -> 262144 bf16
// Fragment value = W[c][k], c = w*32+nf*16+(lane&15), k = kt*32+(lane>>4)*8+e.
__global__ void pack_w(const float* __restrict__ bbWx, const float* __restrict__ bbWh,
                       const float* __restrict__ uWx, const float* __restrict__ spWx,
                       bf16_t* __restrict__ PZ, bf16_t* __restrict__ PH,
                       bf16_t* __restrict__ PU) {
  int i0 = blockIdx.x * blockDim.x + threadIdx.x;
  int stride = gridDim.x * blockDim.x;
  for (int idx = i0; idx < 147456; idx += stride) {
    int e = idx & 7, lane = (idx >> 3) & 63, ch = idx >> 9;
    int w = ch / 36, r36 = ch - w * 36, kt = r36 >> 2, nf = (r36 >> 1) & 1, zr = r36 & 1;
    int l15 = lane & 15, q = lane >> 4;
    int c = w * 32 + nf * 16 + l15;
    int k = kt * 32 + q * 8 + e;
    float v = 0.f;
    if (k < 256) v = bbWh[(zr * 256 + c) * 256 + k];
    else if (k < 256 + FIN) v = bbWx[(zr * 256 + c) * FIN + (k - 256)];
    PZ[idx] = (bf16_t)v;
  }
  for (int idx = i0; idx < 73728; idx += stride) {
    int e = idx & 7, lane = (idx >> 3) & 63, ch = idx >> 9;
    int w = ch / 18, r18 = ch - w * 18, kt = r18 >> 1, nf = r18 & 1;
    int l15 = lane & 15, q = lane >> 4;
    int c = w * 32 + nf * 16 + l15;
    int k = kt * 32 + q * 8 + e;
    float v = 0.f;
    if (k < 256) v = bbWh[(512 + c) * 256 + k];
    else if (k < 256 + FIN) v = bbWx[(512 + c) * FIN + (k - 256)];
    PH[idx] = (bf16_t)v;
  }
  for (int idx = i0; idx < 262144; idx += stride) {
    int e = idx & 7, lane = (idx >> 3) & 63, ch = idx >> 9;
    int half = ch >> 8, r256 = ch & 255;
    int w = r256 >> 5, r32 = r256 & 31, kt = r32 >> 2, g = (r32 >> 1) & 1, nf = r32 & 1;
    int l15 = lane & 15, q = lane >> 4;
    int j = w * 32 + nf * 16 + l15;
    int gate = g * 2;
    int k = kt * 32 + q * 8 + e;
    const float* W = half ? spWx : uWx;
    PU[idx] = (bf16_t)W[(gate * 256 + j) * 256 + k];
  }
}

// ---------------- fused persistent sequence kernel ----------------
// 512 threads = 8 waves; each wave owns a 32-col strip of the 64-row tile.
// 68KB LDS -> 2 blocks/CU -> 16 waves/CU = 4 waves/SIMD (2x latency hiding
// vs round 5). Per-wave regs: 32 acc + 16 zpk + 24 frags + ~25 misc <= 128
// (enforced by __launch_bounds__(512,4)) -> no scratch spills -> L2 stays
// weight-resident. Single-accumulator passes throughout.
__global__ __launch_bounds__(512, 4) void fused_seq(
    const float* __restrict__ X,
    const bf16_t* __restrict__ PZ, const bf16_t* __restrict__ PH,
    const bf16_t* __restrict__ PU,
    const float* __restrict__ bbx, const float* __restrict__ bbh,
    const float* __restrict__ ubx, const float* __restrict__ ubh,
    const float* __restrict__ spbx, const float* __restrict__ spbh,
    const float* __restrict__ Wu, const float* __restrict__ buv,
    const float* __restrict__ Ws, const float* __restrict__ bsv,
    const float* __restrict__ Wp, const float* __restrict__ bpv,
    float* __restrict__ out) {
  __shared__ __align__(16) bf16_t Hm[64 * 256];  // 32768 B, swizzled H tile
  __shared__ __align__(16) bf16_t Ha[64 * 32];   // 4096 B, aug cols (X|pad)
  __shared__ __align__(16) bf16_t Rm[64 * 256];  // 32768 B, rH / zz / hs tile
  char* const Hmb = (char*)Hm;
  char* const Hab = (char*)Ha;
  char* const Rmb = (char*)Rm;

  const int tid = threadIdx.x;
  const int lane = tid & 63, l15 = tid & 15, quad = (tid & 63) >> 4, wave = tid >> 6;
  const int rowBase = blockIdx.x * 64;
  const int srow = tid >> 3, sj = tid & 7, sm = rowBase + srow;

  const bf16_t* const pz0 = PZ + wave * 18432 + lane * 8;
  const bf16_t* const ph0 = PH + wave * 9216 + lane * 8;
  const bf16_t* const pu0 = PU + wave * 16384 + lane * 8;
  const bf16_t* const pu1 = PU + 131072 + wave * 16384 + lane * 8;

  // ---- init: H = 0, aug = [X_0 | 0] (ALL 4096 B of Ha: pads must be 0) ----
  {
    uint4 z4 = make_uint4(0u, 0u, 0u, 0u);
    for (int i = tid; i < 2048; i += 512) ((uint4*)Hmb)[i] = z4;
    if (tid < 256) ((uint4*)Hab)[tid] = z4;
  }
  __syncthreads();
  if (sm < NN) {
    bf16_t* xr = (bf16_t*)(Hab + (srow << 6));
    const float* xp = X + (long)sm * FIN;
    xr[sj] = (bf16_t)xp[sj];
    if (sj + 8 < FIN) xr[sj + 8] = (bf16_t)xp[sj + 8];
  }
  __syncthreads();

#pragma unroll 1
  for (int t = 0; t < TT; ++t) {
    v2bf zpk[4][2][2];  // z gate, bf16-packed (16 VGPRs), lives through phase 2

    // ============ phase 1a: z-gemm (K=288) ============
    {
      v4f az[4][2] = {};
#pragma unroll
      for (int kt = 0; kt < 9; ++kt) {
        v8bf a[4];
#pragma unroll
        for (int mf = 0; mf < 4; ++mf) {
          if (kt < 8)
            a[mf] = *(const v8bf*)(Hmb + ((mf * 16 + l15) << 9) +
                                   ((kt * 64 + quad * 16) ^ ((l15 & 7) << 4)));
          else
            a[mf] = *(const v8bf*)(Hab + ((mf * 16 + l15) << 6) + quad * 16);
        }
        const bf16_t* p = pz0 + kt * 2048;
        v8bf bz[2];
#pragma unroll
        for (int nf = 0; nf < 2; ++nf) bz[nf] = *(const v8bf*)(p + nf * 1024);
#pragma unroll
        for (int mf = 0; mf < 4; ++mf)
#pragma unroll
          for (int nf = 0; nf < 2; ++nf) MFMA16(a[mf], bz[nf], az[mf][nf]);
      }
#pragma unroll
      for (int nf = 0; nf < 2; ++nf) {
        const int c = wave * 32 + nf * 16 + l15;
        const float bz_ = bbx[c] + bbh[c];
#pragma unroll
        for (int mf = 0; mf < 4; ++mf)
#pragma unroll
          for (int rg = 0; rg < 4; ++rg)
            zpk[mf][nf][rg >> 1][rg & 1] = (bf16_t)sigm_(az[mf][nf][rg] + bz_);
      }
    }

    // ============ phase 1b: r-gemm ============
    {
      v4f ar[4][2] = {};
#pragma unroll
      for (int kt = 0; kt < 9; ++kt) {
        v8bf a[4];
#pragma unroll
        for (int mf = 0; mf < 4; ++mf) {
          if (kt < 8)
            a[mf] = *(const v8bf*)(Hmb + ((mf * 16 + l15) << 9) +
                                   ((kt * 64 + quad * 16) ^ ((l15 & 7) << 4)));
          else
            a[mf] = *(const v8bf*)(Hab + ((mf * 16 + l15) << 6) + quad * 16);
        }
        const bf16_t* p = pz0 + kt * 2048 + 512;
        v8bf br[2];
#pragma unroll
        for (int nf = 0; nf < 2; ++nf) br[nf] = *(const v8bf*)(p + nf * 1024);
#pragma unroll
        for (int mf = 0; mf < 4; ++mf)
#pragma unroll
          for (int nf = 0; nf < 2; ++nf) MFMA16(a[mf], br[nf], ar[mf][nf]);
      }
      // epi: rH -> Rm
#pragma unroll
      for (int nf = 0; nf < 2; ++nf) {
        const int c = wave * 32 + nf * 16 + l15;
        const float br_ = bbx[256 + c] + bbh[256 + c];
#pragma unroll
        for (int mf = 0; mf < 4; ++mf)
#pragma unroll
          for (int rg = 0; rg < 4; ++rg) {
            const int m = mf * 16 + quad * 4 + rg;
            const int off = (m << 9) + ((c * 2) ^ ((m & 7) << 4));
            const float hp = (float)*(const bf16_t*)(Hmb + off);
            *(bf16_t*)(Rmb + off) = (bf16_t)(sigm_(ar[mf][nf][rg] + br_) * hp);
          }
      }
    }
    __syncthreads();  // BAR1: Rm (rH) ready

    // prefetch X_{t+1} into registers (hides under phase-2 gemm)
    float xv0 = 0.f, xv1 = 0.f;
    if (t + 1 < TT && sm < NN) {
      const float* xp = X + ((long)(t + 1) * NN + sm) * FIN;
      xv0 = xp[sj];
      if (sj + 8 < FIN) xv1 = xp[sj + 8];
    }

    // ============ phase 2: h_tilde gemm + blend ============
    {
      v4f ah[4][2] = {};
#pragma unroll
      for (int kt = 0; kt < 9; ++kt) {
        v8bf a[4];
#pragma unroll
        for (int mf = 0; mf < 4; ++mf) {
          if (kt < 8)
            a[mf] = *(const v8bf*)(Rmb + ((mf * 16 + l15) << 9) +
                                   ((kt * 64 + quad * 16) ^ ((l15 & 7) << 4)));
          else
            a[mf] = *(const v8bf*)(Hab + ((mf * 16 + l15) << 6) + quad * 16);
        }
        const bf16_t* p = ph0 + kt * 1024;
        v8bf bh[2];
#pragma unroll
        for (int nf = 0; nf < 2; ++nf) bh[nf] = *(const v8bf*)(p + nf * 512);
#pragma unroll
        for (int mf = 0; mf < 4; ++mf)
#pragma unroll
          for (int nf = 0; nf < 2; ++nf) MFMA16(a[mf], bh[nf], ah[mf][nf]);
      }
      // epi2: Hm = z*Hm + (1-z)*tanh(ah+b)
#pragma unroll
      for (int nf = 0; nf < 2; ++nf) {
        const int c = wave * 32 + nf * 16 + l15;
        const float bh_ = bbx[512 + c] + bbh[512 + c];
#pragma unroll
        for (int mf = 0; mf < 4; ++mf)
#pragma unroll
          for (int rg = 0; rg < 4; ++rg) {
            const int m = mf * 16 + quad * 4 + rg;
            const int off = (m << 9) + ((c * 2) ^ ((m & 7) << 4));
            const float htl = tanh_(ah[mf][nf][rg] + bh_);
            const float z = (float)zpk[mf][nf][rg >> 1][rg & 1];
            const float hp = (float)*(const bf16_t*)(Hmb + off);
            *(bf16_t*)(Hmb + off) = (bf16_t)(z * hp + (1.f - z) * htl);
          }
      }
    }
    __syncthreads();  // BAR2: Hm updated; Rm free

    // stage X_{t+1} into Ha (readers are next-t phases, behind later barriers)
    {
      bf16_t* xr = (bf16_t*)(Hab + (srow << 6));
      xr[sj] = (bf16_t)xv0;
      if (sj + 8 < FIN) xr[sj + 8] = (bf16_t)xv1;
    }

    // ============ phase 3: gru_u / gru_sp (H=None) + heads ============
#pragma unroll 1
    for (int half = 0; half < 2; ++half) {
      const bf16_t* puh = half ? pu1 : pu0;
      const float* gbx = half ? spbx : ubx;
      const float* gbh = half ? spbh : ubh;
      // ---- z-gate pass: zz -> Rm (thread-owned cells) ----
      {
        v4f au[4][2] = {};
#pragma unroll
        for (int kt = 0; kt < 8; ++kt) {
          v8bf a[4];
#pragma unroll
          for (int mf = 0; mf < 4; ++mf)
            a[mf] = *(const v8bf*)(Hmb + ((mf * 16 + l15) << 9) +
                                   ((kt * 64 + quad * 16) ^ ((l15 & 7) << 4)));
          const bf16_t* p = puh + kt * 2048;
          v8bf bu[2];
#pragma unroll
          for (int nf = 0; nf < 2; ++nf) bu[nf] = *(const v8bf*)(p + nf * 512);
#pragma unroll
          for (int mf = 0; mf < 4; ++mf)
#pragma unroll
            for (int nf = 0; nf < 2; ++nf) MFMA16(a[mf], bu[nf], au[mf][nf]);
        }
#pragma unroll
        for (int nf = 0; nf < 2; ++nf) {
          const int j = wave * 32 + nf * 16 + l15;
          const float b0 = gbx[j] + gbh[j];
#pragma unroll
          for (int mf = 0; mf < 4; ++mf)
#pragma unroll
            for (int rg = 0; rg < 4; ++rg) {
              const int r = mf * 16 + quad * 4 + rg;
              *(bf16_t*)(Rmb + (r << 9) + ((j * 2) ^ ((r & 7) << 4))) =
                  (bf16_t)sigm_(au[mf][nf][rg] + b0);
            }
        }
      }
      // ---- h-gate pass: hs = (1-zz)*tanh -> Rm (same cells) ----
      {
        v4f au[4][2] = {};
#pragma unroll
        for (int kt = 0; kt < 8; ++kt) {
          v8bf a[4];
#pragma unroll
          for (int mf = 0; mf < 4; ++mf)
            a[mf] = *(const v8bf*)(Hmb + ((mf * 16 + l15) << 9) +
                                   ((kt * 64 + quad * 16) ^ ((l15 & 7) << 4)));
          const bf16_t* p = puh + kt * 2048 + 1024;
          v8bf bu[2];
#pragma unroll
          for (int nf = 0; nf < 2; ++nf) bu[nf] = *(const v8bf*)(p + nf * 512);
#pragma unroll
          for (int mf = 0; mf < 4; ++mf)
#pragma unroll
            for (int nf = 0; nf < 2; ++nf) MFMA16(a[mf], bu[nf], au[mf][nf]);
        }
#pragma unroll
        for (int nf = 0; nf < 2; ++nf) {
          const int j = wave * 32 + nf * 16 + l15;
          const float b1 = gbx[512 + j] + gbh[512 + j];
#pragma unroll
          for (int mf = 0; mf < 4; ++mf)
#pragma unroll
            for (int rg = 0; rg < 4; ++rg) {
              const int r = mf * 16 + quad * 4 + rg;
              bf16_t* cell = (bf16_t*)(Rmb + (r << 9) + ((j * 2) ^ ((r & 7) << 4)));
              const float zz = (float)*cell;  // own cell, written by this thread
              const float ht = tanh_(au[mf][nf][rg] + b1);
              *cell = (bf16_t)((1.f - zz) * ht);
            }
        }
      }
      __syncthreads();  // hs tile ready
      if (half == 0) {
        if (tid < 192) {
          const int r = tid / 3, k = tid - r * 3, m = rowBase + r;
          if (m < NN) {
            float s = 0.f;
            for (int j = 0; j < 256; j += 8) {
              v8bf hv = *(const v8bf*)(Rmb + (r << 9) + ((j * 2) ^ ((r & 7) << 4)));
              const float* w = Wu + k * 256 + j;
#pragma unroll
              for (int jj = 0; jj < 8; ++jj) s += (float)hv[jj] * w[jj];
            }
            out[(long)t * (NN * 3) + (long)m * 3 + k] = s + buv[k];
          }
        }
      } else {
        if (tid < 128) {
          const int r = tid >> 1, which = tid & 1, m = rowBase + r;
          if (m < NN) {
            const float* W = which ? Wp : Ws;
            float s = 0.f;
            for (int j = 0; j < 256; j += 8) {
              v8bf hv = *(const v8bf*)(Rmb + (r << 9) + ((j * 2) ^ ((r & 7) << 4)));
#pragma unroll
              for (int jj = 0; jj < 8; ++jj) s += (float)hv[jj] * W[j + jj];
            }
            s += which ? bpv[0] : bsv[0];
            out[(long)TT * NN * 3 + (long)which * TT * NN + (long)t * NN + m] = s;
          }
        }
      }
      __syncthreads();  // head reads done before Rm is overwritten
    }
  }
}

extern "C" void kernel_launch(void* const* d_in, const int* in_sizes, int n_in,
                              void* d_out, int out_size, void* d_ws, size_t ws_size,
                              hipStream_t stream) {
  const float* X    = (const float*)d_in[0];
  // d_in[1] edge_index: unused (ChebConv K=1 ignores edges)
  const float* bbWx = (const float*)d_in[2];
  const float* bbbx = (const float*)d_in[3];
  const float* bbWh = (const float*)d_in[4];
  const float* bbbh = (const float*)d_in[5];
  const float* uWx  = (const float*)d_in[6];
  const float* ubx  = (const float*)d_in[7];
  const float* ubh  = (const float*)d_in[9];   // u_Wh (d_in[8]) dead: H=None
  const float* spWx = (const float*)d_in[10];
  const float* spbx = (const float*)d_in[11];
  const float* spbh = (const float*)d_in[13];  // sp_Wh (d_in[12]) dead
  const float* Wu   = (const float*)d_in[14];
  const float* buv  = (const float*)d_in[15];
  const float* Ws   = (const float*)d_in[16];
  const float* bsv  = (const float*)d_in[17];
  const float* Wp   = (const float*)d_in[18];
  const float* bpv  = (const float*)d_in[19];
  float* out = (float*)d_out;

  char* ws = (char*)d_ws;
  bf16_t* PZ = (bf16_t*)(ws);                  // 147456*2 = 294912
  bf16_t* PH = (bf16_t*)(ws + 294912);         //  73728*2 = 147456
  bf16_t* PU = (bf16_t*)(ws + 442368);         // 262144*2 = 524288
  if (ws_size < (size_t)966656) return;

  pack_w<<<dim3(192), dim3(256), 0, stream>>>(bbWx, bbWh, uWx, spWx, PZ, PH, PU);
  fused_seq<<<dim3(MB), dim3(512), 0, stream>>>(X, PZ, PH, PU, bbbx, bbbh,
                                                ubx, ubh, spbx, spbh,
                                                Wu, buv, Ws, bsv, Wp, bpv, out);
}